// Round 16
// baseline (102.708 us; speedup 1.0000x reference)
//
#include <hip/hip_runtime.h>
#include <hip/hip_bf16.h>
#include <math.h>

// MMD (InfoVAE RBF kernel), N=8192, D=128, fp32 in, scalar fp32 out.
//
// Round 26 = r25/r18 base + A-fragment DOUBLE-BUFFER (the one untried
// latency lever) + ar moved to epilogue (register headroom enabler).
//   r25 post-mortem: session-variance confirmed (identical source ->
//   identical 45.4us mmd at 428 GB/s); total 100.56us best; the ~55us
//   total-mmd gap is harness-fixed (insensitive to launch count).
//   All leverage is inside mmd's 45.4us.
//   Critical-path re-derivation: per slice, LOADA's 8 ds_read_b128
//   (~120cy latency) issue immediately before the consuming MFMA
//   cluster -> ~120cy exposed per slice ~= 480cy/tile ~= 32% of the
//   ~1500cy tile time. Every prior variant had this; only B ever got
//   a dbuf. Fix: aA/aB ping-pong - slice s+1's ds_reads issue before
//   slice s's MFMA cluster (A-LDS immutable during the J-loop, so
//   early reads are trivially valid):
//     slice0: LOADB(b1,pl1); LOADA(aB,1); | MFMAS(b0,aA)
//     slice1: LOADB(b0,pl2); LOADA(aA,2); | MFMAS(b1,aB)
//     slice2: LOADB(b1,pl3); LOADA(aB,3); | MFMAS(b0,aA)
//     slice3: LOADB(b0,n pl0); LOADA(aA,0); | MFMAS(b1,aB)  // aA = next
//     tile's plane0 (A is tile-invariant; same bytes every tile).
//   Numerics: operand bytes, per-element MFMA chain (planes 0..3
//   ascending) and epilogue formula bit-identical to r25 (5.960464e-08);
//   ar reloaded per tile in the epilogue reads the same address (L1-hot,
//   same values). Segment-end __syncthreads waits own lgkm before the
//   barrier, so the speculative last LOADA(aA,0) drains before the next
//   segment's A-DMA overwrites LDS.
//   Registers: aA16+aB16+b0 16+b1 16 + addr/misc ~24 = ~88 VGPR + 64
//   AGPR acc = ~152 unified <= 170 -> 3 waves/SIMD kept (launch_bounds
//   (256,3)). Spill tell: VGPR>=120 or WRITE_SIZE inflation.
//   Everything else r25 verbatim: pair-balanced triangle SPLIT=12, 768
//   blocks = 3/CU, A panel DMA-staged once/segment (single vmcnt(0)+
//   barrier), B direct L2->reg dbuf issued before each cluster,
//   barrier-free J-loop, separate finish kernel.

#define NN 8192
#define DD 128
#define TZ 16384
#define SPLIT 12
#define NBLK (64 * SPLIT)                  // 768

typedef __attribute__((ext_vector_type(8))) short bf16x8;
typedef __attribute__((ext_vector_type(4))) float f32x4;
typedef __attribute__((ext_vector_type(2))) float f32x2;

#if __has_builtin(__builtin_amdgcn_exp2f)
#define EXP2F __builtin_amdgcn_exp2f
#else
#define EXP2F exp2f
#endif

constexpr float LOG2E = 0x1.715476p+0f;
constexpr float S2 = LOG2E / 8192.0f;              // 2*log2e/16384

constexpr size_t PLANE = 1048576;                  // 16384 rows x 64 B

#define LDS_RED 32768

// ---- ws layout ----
constexpr size_t WS_NORM = 2048;                   // sums: 256 fp64 slots
constexpr size_t WS_Z    = WS_NORM + (size_t)TZ * sizeof(float);

__device__ __forceinline__ void gload_lds16(const void* g, void* l) {
  __builtin_amdgcn_global_load_lds(
      (const __attribute__((address_space(1))) void*)g,
      (__attribute__((address_space(3))) void*)l, 16, 0, 0);
}

__global__ __launch_bounds__(256) void prep(
    const float* __restrict__ X, const float* __restrict__ Y,
    char* __restrict__ Zs, float* __restrict__ normZ,
    double* __restrict__ sums) {
  if (blockIdx.x == 0) sums[threadIdx.x] = 0.0;    // 256 slots

  const int row = blockIdx.x * 4 + (threadIdx.x >> 6);
  const int lane = threadIdx.x & 63;
  const float* __restrict__ src =
      (row < NN) ? (X + (size_t)row * DD) : (Y + (size_t)(row - NN) * DD);
  const float2 v = *reinterpret_cast<const float2*>(src + 2 * lane);

  float n = v.x * v.x + v.y * v.y;

  // K-slice plane store, chunk pre-swizzled (r14-verified).
  const int ks = lane >> 4;
  const int quadc = (lane >> 2) & 3;
  const int inner = (lane & 3) * 4;
  char* dst = Zs + (size_t)ks * PLANE + (size_t)row * 64 +
              ((quadc ^ ((row >> 1) & 3)) << 4) + inner;
  *reinterpret_cast<__hip_bfloat162*>(dst) =
      __hip_bfloat162{__float2bfloat16(v.x), __float2bfloat16(v.y)};

#pragma unroll
  for (int o = 32; o > 0; o >>= 1) n += __shfl_down(n, o);
  if (lane == 0) normZ[row] = n * (-LOG2E / 16384.0f);  // pre-scaled
}

__global__ __launch_bounds__(256, 3) void mmd_mfma(
    const char* __restrict__ Zs, const float* __restrict__ normZ,
    double* __restrict__ sums) {
  __shared__ alignas(16) char lds[LDS_RED + 64];   // A planes 4x8KB + red

  const int bid = blockIdx.x;
  const int p = bid / SPLIT, s = bid % SPLIT;
  const int q = 127 - p;
  const int n1 = (127 - p - s) / SPLIT + 1;
  const int u0 = s + SPLIT * n1 - (128 - p);       // >= 0 by construction
  const int n2 = (u0 <= p) ? (p - u0) / SPLIT + 1 : 0;

  const int segI[2]  = {p, q};
  const int segJ0[2] = {p + s, q + u0};
  const int segN[2]  = {n1, n2};

  const int tid = threadIdx.x;
  const int lane = tid & 63, wave = tid >> 6;      // 4 waves
  const int wr = wave >> 1, wc = wave & 1;         // 2x2: 64x64 per wave
  const int lr = lane & 15, quad = lane >> 4;

  // r13/r14-verified swizzle (identical on read & prep-store sides).
  const int csw = (quad ^ ((lr >> 1) & 3)) << 4;
  const char* aRd = lds + (wr * 64 + lr) * 64 + csw;
  const size_t bOff = (size_t)(wc * 64 + lr) * 64 + csw;

  bf16x8 aA[4], aB[4], b0[4], b1[4];

#define LOADA(dst, ks) do {                                                 \
    _Pragma("unroll")                                                       \
    for (int i = 0; i < 4; ++i)                                             \
      dst[i] = *reinterpret_cast<const bf16x8*>(aRd + (ks) * 8192 + i * 1024);\
  } while (0)

#define LOADB(dst, base, pl) do {                                           \
    _Pragma("unroll")                                                       \
    for (int j = 0; j < 4; ++j)                                             \
      dst[j] = *reinterpret_cast<const bf16x8*>(                            \
          (base) + (size_t)(pl) * PLANE + j * 1024);                        \
  } while (0)

#define MFMAS(bb, aa) do {                                                  \
    __builtin_amdgcn_s_setprio(1);                                          \
    _Pragma("unroll")                                                       \
    for (int i = 0; i < 4; ++i)                                             \
      _Pragma("unroll")                                                     \
      for (int j = 0; j < 4; ++j)                                           \
        acc[i][j] = __builtin_amdgcn_mfma_f32_16x16x32_bf16(                \
            aa[i], bb[j], acc[i][j], 0, 0, 0);                              \
    __builtin_amdgcn_s_setprio(0);                                          \
  } while (0)

  const f32x2 s2v = {S2, S2};
  double blockAcc = 0.0;

  for (int seg = 0; seg < 2; ++seg) {
    const int I = segI[seg];
    const int nIter = segN[seg];
    if (nIter == 0) continue;                      // block-uniform
    int J = segJ0[seg];
    const float* nzA = normZ + I * 128 + wr * 64;

    // ---- stage A panel once: 4 planes x 8 KB, 2 issues/wave/plane ----
    const char* srcA0 = Zs + (size_t)(I * 128 + wave * 32) * 64 + lane * 16;
    char* ldwA = lds + wave * 2048;
#pragma unroll
    for (int ks = 0; ks < 4; ++ks) {
      gload_lds16(srcA0 + (size_t)ks * PLANE,        ldwA + ks * 8192);
      gload_lds16(srcA0 + (size_t)ks * PLANE + 1024, ldwA + ks * 8192 + 1024);
    }

    // First-tile slice-0 B preload (drained by the same vmcnt(0)).
    const char* bbase = Zs + (size_t)J * 8192 + bOff;
    LOADB(b0, bbase, 0);
    asm volatile("s_waitcnt vmcnt(0)\n\ts_barrier" ::: "memory");
    LOADA(aA, 0);                                  // slice-0 A prefetch

    for (int it = 0; it < nIter; ++it) {
      const char* bnext = (it + 1 < nIter) ? bbase + SPLIT * 8192 : bbase;
      f32x4 acc[4][4] = {};

      // slice 0: prefetch B pl1 + A slice1; compute (b0, aA)
      LOADB(b1, bbase, 1);
      LOADA(aB, 1);
      __builtin_amdgcn_sched_barrier(0);
      MFMAS(b0, aA);

      // slice 1: prefetch B pl2 + A slice2; compute (b1, aB)
      LOADB(b0, bbase, 2);
      LOADA(aA, 2);
      __builtin_amdgcn_sched_barrier(0);
      MFMAS(b1, aB);

      // slice 2: prefetch B pl3 + A slice3; compute (b0, aA)
      LOADB(b1, bbase, 3);
      LOADA(aB, 3);
      __builtin_amdgcn_sched_barrier(0);
      MFMAS(b0, aA);

      // slice 3: prefetch NEXT tile B pl0 + A slice0 (tile-invariant);
      // compute (b1, aB)
      LOADB(b0, bnext, 0);
      LOADA(aA, 0);
      __builtin_amdgcn_sched_barrier(0);
      MFMAS(b1, aB);

      // ---- epilogue: ar (L1-hot, tile-invariant addr) + cb direct ----
      f32x4 ar[4];
#pragma unroll
      for (int i = 0; i < 4; ++i)
        ar[i] = *reinterpret_cast<const f32x4*>(nzA + i * 16 + quad * 4);
      const float* nzB = normZ + J * 128 + wc * 64;
      float cb[4];
#pragma unroll
      for (int j = 0; j < 4; ++j) cb[j] = nzB[j * 16 + lr];

      f32x2 part01 = {0.f, 0.f}, part23 = {0.f, 0.f};
#pragma unroll
      for (int i = 0; i < 4; ++i) {
        const f32x2 ar01 = {ar[i].x, ar[i].y};
        const f32x2 ar23 = {ar[i].z, ar[i].w};
#pragma unroll
        for (int j = 0; j < 4; ++j) {
          const f32x2 rb2 = {cb[j], cb[j]};
          const f32x2 base01 = ar01 + rb2;
          const f32x2 base23 = ar23 + rb2;
          const f32x2 acc01 = {acc[i][j][0], acc[i][j][1]};
          const f32x2 acc23 = {acc[i][j][2], acc[i][j][3]};
          const f32x2 arg01 = __builtin_elementwise_fma(acc01, s2v, base01);
          const f32x2 arg23 = __builtin_elementwise_fma(acc23, s2v, base23);
          part01 += (f32x2){EXP2F(arg01.x), EXP2F(arg01.y)};
          part23 += (f32x2){EXP2F(arg23.x), EXP2F(arg23.y)};
        }
      }
      const f32x2 ps = part01 + part23;
      double w = ((I < 64) == (J < 64)) ? 1.0 : -1.0;  // X/Y boundary: 64
      if (I != J) w += w;
      blockAcc += (double)(ps.x + ps.y) * w;

      J += SPLIT;
      bbase = bnext;
    }

    // Segment end: waves drain own lgkm (incl. speculative LOADA) before
    // the barrier; next segment's A-DMA only after all waves arrive.
    __syncthreads();
  }

#undef LOADA
#undef LOADB
#undef MFMAS

#pragma unroll
  for (int o = 32; o > 0; o >>= 1) blockAcc += __shfl_down(blockAcc, o);
  double* red = reinterpret_cast<double*>(lds + LDS_RED);
  if (lane == 0) red[wave] = blockAcc;
  __syncthreads();
  if (tid == 0)
    atomicAdd(&sums[bid & 255], red[0] + red[1] + red[2] + red[3]);
}

__global__ void finish(const double* __restrict__ s, float* __restrict__ out) {
  double v = s[threadIdx.x] + s[threadIdx.x + 64] + s[threadIdx.x + 128] +
             s[threadIdx.x + 192];
#pragma unroll
  for (int o = 32; o > 0; o >>= 1) v += __shfl_down(v, o);
  if (threadIdx.x == 0)
    out[0] = (float)(v * (1.0 / ((double)NN * (double)NN)));
}

extern "C" void kernel_launch(void* const* d_in, const int* in_sizes, int n_in,
                              void* d_out, int out_size, void* d_ws, size_t ws_size,
                              hipStream_t stream) {
  const float* y_inputs = (const float*)d_in[0];  // "inputs"
  const float* x_true   = (const float*)d_in[1];  // "true_samples"
  float* out = (float*)d_out;

  char* ws = (char*)d_ws;
  double* sums = (double*)ws;                     // 256 fp64 partial slots
  float* normZ = (float*)(ws + WS_NORM);
  char* Zs = ws + WS_Z;

  prep<<<TZ / 4, 256, 0, stream>>>(x_true, y_inputs, Zs, normZ, sums);
  mmd_mfma<<<NBLK, 256, 0, stream>>>(Zs, normZ, sums);
  finish<<<1, 64, 0, stream>>>(sums, out);
}